// Round 1
// baseline (14719.398 us; speedup 1.0000x reference)
//
#include <hip/hip_runtime.h>
#include <hip/hip_bf16.h>
#include <cstdint>
#include <cstddef>

typedef short short8 __attribute__((ext_vector_type(8)));
typedef float f32x4 __attribute__((ext_vector_type(4)));

#define TT 512
#define BB 64
#define DD 1024
#define LL 1024

// ---------------------------------------------------------------------------
// Prep 1: transpose + convert 4 gate weights [2048,1024] fp32 -> Wt[c][k] bf16,
// c = g*1024 + l, k contiguous. (Verified R1/R2.)
// ---------------------------------------------------------------------------
__global__ __launch_bounds__(256) void transpose_w(
    const float* __restrict__ Wf, const float* __restrict__ Wi,
    const float* __restrict__ Wo, const float* __restrict__ Wg,
    __hip_bfloat16* __restrict__ Wt) {
  __shared__ float tile[32][33];
  const int g = blockIdx.z;
  const float* W = (g == 0) ? Wf : (g == 1) ? Wi : (g == 2) ? Wo : Wg;
  const int k0 = blockIdx.x * 32, l0 = blockIdx.y * 32;
  const int c = threadIdx.x & 31, r0 = threadIdx.x >> 5;
#pragma unroll
  for (int rr = 0; rr < 4; ++rr) {
    const int kk = r0 + rr * 8;
    tile[kk][c] = W[(size_t)(k0 + kk) * LL + (l0 + c)];
  }
  __syncthreads();
#pragma unroll
  for (int rr = 0; rr < 4; ++rr) {
    const int ll = r0 + rr * 8;
    Wt[((size_t)(g * LL + l0 + ll) << 11) + (k0 + c)] = __float2bfloat16(tile[c][ll]);
  }
}

// ---------------------------------------------------------------------------
// Prep 2: x fp32 -> bf16.
// ---------------------------------------------------------------------------
__global__ __launch_bounds__(256) void xconv(const float* __restrict__ x,
                                             __hip_bfloat16* __restrict__ xbf) {
  const size_t i = (size_t)blockIdx.x * 256 + threadIdx.x;
  const float4 v = ((const float4*)x)[i];
  union { __hip_bfloat16 b[4]; uint2 u; } o;
  o.b[0] = __float2bfloat16(v.x);
  o.b[1] = __float2bfloat16(v.y);
  o.b[2] = __float2bfloat16(v.z);
  o.b[3] = __float2bfloat16(v.w);
  ((uint2*)xbf)[i] = o.u;
}

// ---------------------------------------------------------------------------
// PERSISTENT LSTM: one launch, 256 blocks (1/CU, co-resident) x 512 threads.
// Block owns 4 latent cols -> 16 gate cols. Wave (bt=w&3, kp=w>>2):
//   kp=0 waves: x_t GEMM half (K 0..1023)  — never wait on the barrier.
//   kp=1 waves: h_{t-1} GEMM half          — spin on 256 epoch flags first.
// Weights: 32 x short8 = 128 VGPRs per lane, loaded ONCE (immune to L2 inv).
// c: fp32 register in its pointwise thread. h: bf16 ping-pong in global.
// Protocol/step: [kp=1: spin flags>=t, acquire fence] -> GEMM -> LDS reduce
//  -> pointwise (tid<256) -> h/out stores -> sync (vmcnt drain) -> tid0
//  release-store flags[bid]=t+1 (buffer_wbl2). Spin-before-read doubles as
//  the WAR guard on the 2-buffer h ping-pong.
// ---------------------------------------------------------------------------
__global__ __launch_bounds__(512, 2) void lstm_persist(
    const __hip_bfloat16* __restrict__ xbf, const __hip_bfloat16* __restrict__ Wt,
    const float* __restrict__ bfv, const float* __restrict__ biv,
    const float* __restrict__ bov, const float* __restrict__ bgv,
    float* __restrict__ out,
    __hip_bfloat16* __restrict__ hb0, __hip_bfloat16* __restrict__ hb1,
    int* __restrict__ flags) {
  __shared__ float gs[64][17];  // +1 pad: quads land on distinct banks

  const int tid = threadIdx.x;
  const int lane = tid & 63, w = tid >> 6;
  const int quad = lane >> 4, hc = lane & 15;
  const int bt = w & 3, kp = w >> 2;
  const int bid = blockIdx.x;
  const int l0 = bid * 4;

  // ---- persistent B fragments: col(hc) = (hc>>2)*1024 + l0 + (hc&3) ----
  const int col = ((hc >> 2) << 10) + l0 + (hc & 3);
  const __hip_bfloat16* wb = Wt + ((size_t)col << 11) + (kp << 10) + quad * 8;
  short8 Bf[32];
#pragma unroll
  for (int i = 0; i < 32; ++i) Bf[i] = *(const short8*)(wb + i * 32);

  // A-fragment row offset within z (rows = 16 batches per bt-tile)
  const size_t zoff = ((size_t)((bt << 4) + hc) << 10) + quad * 8;

  // ---- pointwise-thread persistent state (c + biases in registers) ----
  const int pb = tid >> 2, pli = tid & 3, pl = l0 + pli;
  float cr = 0.f, bfr = 0.f, bir = 0.f, bor = 0.f, bgr = 0.f;
  if (tid < 256) { bfr = bfv[pl]; bir = biv[pl]; bor = bov[pl]; bgr = bgv[pl]; }

  for (int t = 0; t < TT; ++t) {
    const __hip_bfloat16* hr = (t & 1) ? hb0 : hb1;  // t=0 reads zeroed hb1
    __hip_bfloat16* hw = (t & 1) ? hb1 : hb0;

    const __hip_bfloat16* za;
    if (kp == 0) {
      za = xbf + ((size_t)t << 16) + zoff;           // x_t: no dependency
    } else {
      if (t > 0) {
#pragma unroll
        for (int i = 0; i < 4; ++i) {                // lane covers 4 of 256 flags
          while (__hip_atomic_load(&flags[lane + (i << 6)], __ATOMIC_RELAXED,
                                   __HIP_MEMORY_SCOPE_AGENT) < t) {
            __builtin_amdgcn_s_sleep(1);             // ease L3 poll pressure
          }
        }
        __builtin_amdgcn_fence(__ATOMIC_ACQUIRE, "agent");  // buffer_inv sc1
      }
      za = hr + zoff;
    }

    // ---- GEMM: 4 groups x 8 k-steps, A depth-2 prefetch, dual acc ----
    f32x4 acc0 = {}, acc1 = {};
    short8 Af[2][8];
#pragma unroll
    for (int i = 0; i < 8; ++i) Af[0][i] = *(const short8*)(za + i * 32);
#pragma unroll
    for (int g = 0; g < 4; ++g) {
      const int cur = g & 1, nxt = cur ^ 1;
      if (g < 3) {
#pragma unroll
        for (int i = 0; i < 8; ++i)
          Af[nxt][i] = *(const short8*)(za + (g + 1) * 256 + i * 32);
      }
#pragma unroll
      for (int i = 0; i < 8; ++i) {
        if (i & 1)
          acc1 = __builtin_amdgcn_mfma_f32_16x16x32_bf16(Af[cur][i], Bf[g * 8 + i], acc1, 0, 0, 0);
        else
          acc0 = __builtin_amdgcn_mfma_f32_16x16x32_bf16(Af[cur][i], Bf[g * 8 + i], acc0, 0, 0, 0);
      }
    }

    // ---- cross-wave (kp) reduction: C/D row=quad*4+r, col=hc ----
    if (kp == 1) {
#pragma unroll
      for (int r = 0; r < 4; ++r)
        gs[(bt << 4) + (quad << 2) + r][hc] = acc0[r] + acc1[r];
    }
    __syncthreads();
    if (kp == 0) {
#pragma unroll
      for (int r = 0; r < 4; ++r)
        gs[(bt << 4) + (quad << 2) + r][hc] += acc0[r] + acc1[r];
    }
    __syncthreads();

    // ---- pointwise LSTM update (fp32), c in register ----
    if (tid < 256) {
      const float fp = gs[pb][0 + pli] + bfr;
      const float ip = gs[pb][4 + pli] + bir;
      const float op = gs[pb][8 + pli] + bor;
      const float gp = gs[pb][12 + pli] + bgr;
      const float fs = 1.0f / (1.0f + __expf(-fp));
      const float is = 1.0f / (1.0f + __expf(-ip));
      const float os = 1.0f / (1.0f + __expf(-op));
      const float gv = tanhf(gp);
      const float cn = fs * cr + is * gv;
      cr = cn;
      const float h = os * tanhf(cn);
      out[(((size_t)t * BB + pb) << 10) + pl] = h;
      hw[((size_t)pb << 10) + pl] = __float2bfloat16(h);
    }
    __syncthreads();  // drain all waves' vmcnt: h/out stores complete in L2
    if (tid == 0)     // release: buffer_wbl2 sc1 -> L3, then flag sc1
      __hip_atomic_store(&flags[bid], t + 1, __ATOMIC_RELEASE,
                         __HIP_MEMORY_SCOPE_AGENT);
  }
}

// ---------------------------------------------------------------------------
extern "C" void kernel_launch(void* const* d_in, const int* in_sizes, int n_in,
                              void* d_out, int out_size, void* d_ws, size_t ws_size,
                              hipStream_t stream) {
  const float* x   = (const float*)d_in[0];
  const float* Wf  = (const float*)d_in[1];
  const float* bfv = (const float*)d_in[2];
  const float* Wi  = (const float*)d_in[3];
  const float* biv = (const float*)d_in[4];
  const float* Wo  = (const float*)d_in[5];
  const float* bov = (const float*)d_in[6];
  const float* Wg  = (const float*)d_in[7];
  const float* bgv = (const float*)d_in[8];
  float* out = (float*)d_out;

  // ws: Wt bf16 [4096][2048] (16 MB) | xbf (64 MB) | hb0,hb1 (256 KB) | flags (1 KB)
  __hip_bfloat16* Wt  = (__hip_bfloat16*)d_ws;
  __hip_bfloat16* xbf = Wt + (size_t)4096 * 2048;
  __hip_bfloat16* hb0 = xbf + (size_t)TT * BB * LL;
  __hip_bfloat16* hb1 = hb0 + (size_t)BB * LL;
  int* flags = (int*)(hb1 + (size_t)BB * LL);

  transpose_w<<<dim3(64, 32, 4), 256, 0, stream>>>(Wf, Wi, Wo, Wg, Wt);
  xconv<<<dim3((TT * BB * LL) / 4 / 256), 256, 0, stream>>>(x, xbf);
  hipMemsetAsync(hb0, 0, (size_t)2 * BB * LL * sizeof(__hip_bfloat16), stream);
  hipMemsetAsync(flags, 0, 256 * sizeof(int), stream);

  lstm_persist<<<256, 512, 0, stream>>>(xbf, Wt, bfv, biv, bov, bgv,
                                        out, hb0, hb1, flags);
}

// Round 3
// 8575.061 us; speedup vs baseline: 1.7165x; 1.7165x over previous
//
#include <hip/hip_runtime.h>
#include <hip/hip_bf16.h>
#include <cstdint>
#include <cstddef>

typedef short short8 __attribute__((ext_vector_type(8)));
typedef float f32x4 __attribute__((ext_vector_type(4)));
typedef unsigned long long u64;

#define TT 512
#define BB 64
#define DD 1024
#define LL 1024

// ---------------------------------------------------------------------------
// Prep 1: transpose + convert 4 gate weights [2048,1024] fp32 -> Wt[c][k] bf16,
// c = g*1024 + l, k contiguous. (Verified R0/R1.)
// ---------------------------------------------------------------------------
__global__ __launch_bounds__(256) void transpose_w(
    const float* __restrict__ Wf, const float* __restrict__ Wi,
    const float* __restrict__ Wo, const float* __restrict__ Wg,
    __hip_bfloat16* __restrict__ Wt) {
  __shared__ float tile[32][33];
  const int g = blockIdx.z;
  const float* W = (g == 0) ? Wf : (g == 1) ? Wi : (g == 2) ? Wo : Wg;
  const int k0 = blockIdx.x * 32, l0 = blockIdx.y * 32;
  const int c = threadIdx.x & 31, r0 = threadIdx.x >> 5;
#pragma unroll
  for (int rr = 0; rr < 4; ++rr) {
    const int kk = r0 + rr * 8;
    tile[kk][c] = W[(size_t)(k0 + kk) * LL + (l0 + c)];
  }
  __syncthreads();
#pragma unroll
  for (int rr = 0; rr < 4; ++rr) {
    const int ll = r0 + rr * 8;
    Wt[((size_t)(g * LL + l0 + ll) << 11) + (k0 + c)] = __float2bfloat16(tile[c][ll]);
  }
}

// ---------------------------------------------------------------------------
// Prep 2: x fp32 -> bf16.
// ---------------------------------------------------------------------------
__global__ __launch_bounds__(256) void xconv(const float* __restrict__ x,
                                             __hip_bfloat16* __restrict__ xbf) {
  const size_t i = (size_t)blockIdx.x * 256 + threadIdx.x;
  const float4 v = ((const float4*)x)[i];
  union { __hip_bfloat16 b[4]; uint2 u; } o;
  o.b[0] = __float2bfloat16(v.x);
  o.b[1] = __float2bfloat16(v.y);
  o.b[2] = __float2bfloat16(v.z);
  o.b[3] = __float2bfloat16(v.w);
  ((uint2*)xbf)[i] = o.u;
}

// ---------------------------------------------------------------------------
// PERSISTENT LSTM v3 — point-to-point sc1 protocol, no wbl2 / no inv.
// 256 blocks (1/CU, co-resident; same geometry R1 proved live) x 512 thr.
// Block owns 4 latent cols -> 16 gate cols. Wave (bt=w&3, kp=w>>2):
//   kp=0: x_t GEMM half (plain cached loads, never waits)
//   kp=1: h_{t-1} GEMM half (bounded spin on flags, then sc1 h loads)
// h: bf16 ping-pong hb0/hb1, written via relaxed-agent atomic stores
// (global_store sc1, write-through to L3) and read via relaxed-agent atomic
// loads (global_load sc1, L2-bypass) -> no stale-L2 hazard, no fences.
// Writer order: sc1 h stores -> s_waitcnt vmcnt(0) (committed to L3) ->
// __syncthreads -> tid0 sc1 flag store. flag=t implies that block finished
// step t-1 INCLUDING its reads of hb[t&1], so overwriting hb[t&1] at step t
// is WAR-safe. Weights/x/biases use plain cached loads -> L2 warm forever.
// Spins are capped: protocol failure => visible wrong answer, never a hang.
// ---------------------------------------------------------------------------
__global__ __launch_bounds__(512, 2) void lstm_persist(
    const __hip_bfloat16* __restrict__ xbf, const __hip_bfloat16* __restrict__ Wt,
    const float* __restrict__ bfv, const float* __restrict__ biv,
    const float* __restrict__ bov, const float* __restrict__ bgv,
    float* __restrict__ out,
    __hip_bfloat16* __restrict__ hb0, __hip_bfloat16* __restrict__ hb1,
    int* __restrict__ flags) {
  __shared__ float gs[64][17];  // +1 pad: quads land on distinct banks

  const int tid = threadIdx.x;
  const int lane = tid & 63, w = tid >> 6;
  const int quad = lane >> 4, hc = lane & 15;
  const int bt = w & 3, kp = w >> 2;
  const int bid = blockIdx.x;
  const int l0 = bid * 4;

  // B fragments: col(hc) = (hc>>2)*1024 + l0 + (hc&3), k-window kp*1024..
  const int col = ((hc >> 2) << 10) + l0 + (hc & 3);
  const __hip_bfloat16* wb = Wt + ((size_t)col << 11) + (kp << 10) + quad * 8;
  short8 Bf[32];
#pragma unroll
  for (int i = 0; i < 32; ++i) Bf[i] = *(const short8*)(wb + i * 32);

  const size_t rowoff = (size_t)((bt << 4) + hc);  // batch row this lane loads

  // ---- pointwise persistent state: tid<128 -> (b = tid>>1, 2 latent cols) ----
  const int pb = tid >> 1, li = (tid & 1) << 1;
  const int plA = l0 + li;
  float cr0 = 0.f, cr1 = 0.f;
  float bf0 = 0, bf1 = 0, bi0 = 0, bi1 = 0, bo0 = 0, bo1 = 0, bg0 = 0, bg1 = 0;
  if (tid < 128) {
    bf0 = bfv[plA]; bf1 = bfv[plA + 1];
    bi0 = biv[plA]; bi1 = biv[plA + 1];
    bo0 = bov[plA]; bo1 = bov[plA + 1];
    bg0 = bgv[plA]; bg1 = bgv[plA + 1];
  }

  for (int t = 0; t < TT; ++t) {
    f32x4 acc0 = {}, acc1 = {};

    if (kp == 0) {
      // ---- x_t GEMM half: plain cached bf16 loads, depth-2 prefetch ----
      const __hip_bfloat16* za = xbf + ((size_t)t << 16) + (rowoff << 10) + quad * 8;
      short8 Af[2][8];
#pragma unroll
      for (int i = 0; i < 8; ++i) Af[0][i] = *(const short8*)(za + i * 32);
#pragma unroll
      for (int g = 0; g < 4; ++g) {
        const int cur = g & 1, nxt = cur ^ 1;
        if (g < 3) {
#pragma unroll
          for (int i = 0; i < 8; ++i)
            Af[nxt][i] = *(const short8*)(za + (g + 1) * 256 + i * 32);
        }
#pragma unroll
        for (int i = 0; i < 8; ++i) {
          if (i & 1)
            acc1 = __builtin_amdgcn_mfma_f32_16x16x32_bf16(Af[cur][i], Bf[g * 8 + i], acc1, 0, 0, 0);
          else
            acc0 = __builtin_amdgcn_mfma_f32_16x16x32_bf16(Af[cur][i], Bf[g * 8 + i], acc0, 0, 0, 0);
        }
      }
    } else if (t > 0) {
      // ---- bounded spin: all 256 blocks published step t-1 ----
      int spins = 0;
#pragma unroll
      for (int i = 0; i < 4; ++i) {
        while (__hip_atomic_load(&flags[lane + (i << 6)], __ATOMIC_RELAXED,
                                 __HIP_MEMORY_SCOPE_AGENT) < t) {
          __builtin_amdgcn_s_sleep(1);
          if (++spins > (1 << 18)) break;  // fail visible, never hang
        }
      }
      asm volatile("" ::: "memory");  // keep h loads below the spin

      // ---- h GEMM half: sc1 (L2-bypass) 8B loads straight from L3 ----
      const __hip_bfloat16* hr = (t & 1) ? hb0 : hb1;
      const u64* hp = (const u64*)(hr + (rowoff << 10) + quad * 8);
      union frag { short8 s; u64 u[2]; };
      frag Ah[2][8];
#pragma unroll
      for (int i = 0; i < 8; ++i) {
        Ah[0][i].u[0] = __hip_atomic_load(hp + i * 8, __ATOMIC_RELAXED,
                                          __HIP_MEMORY_SCOPE_AGENT);
        Ah[0][i].u[1] = __hip_atomic_load(hp + i * 8 + 1, __ATOMIC_RELAXED,
                                          __HIP_MEMORY_SCOPE_AGENT);
      }
#pragma unroll
      for (int g = 0; g < 4; ++g) {
        const int cur = g & 1, nxt = cur ^ 1;
        if (g < 3) {
#pragma unroll
          for (int i = 0; i < 8; ++i) {
            Ah[nxt][i].u[0] = __hip_atomic_load(hp + (g + 1) * 64 + i * 8,
                                                __ATOMIC_RELAXED, __HIP_MEMORY_SCOPE_AGENT);
            Ah[nxt][i].u[1] = __hip_atomic_load(hp + (g + 1) * 64 + i * 8 + 1,
                                                __ATOMIC_RELAXED, __HIP_MEMORY_SCOPE_AGENT);
          }
        }
#pragma unroll
        for (int i = 0; i < 8; ++i) {
          if (i & 1)
            acc1 = __builtin_amdgcn_mfma_f32_16x16x32_bf16(Ah[cur][i].s, Bf[g * 8 + i], acc1, 0, 0, 0);
          else
            acc0 = __builtin_amdgcn_mfma_f32_16x16x32_bf16(Ah[cur][i].s, Bf[g * 8 + i], acc0, 0, 0, 0);
        }
      }
    }
    // (kp==1, t==0: h = 0, acc stays 0)

    // ---- cross-wave (kp) reduction: C/D row=quad*4+r, col=hc ----
    if (kp == 1) {
#pragma unroll
      for (int r = 0; r < 4; ++r)
        gs[(bt << 4) + (quad << 2) + r][hc] = acc0[r] + acc1[r];
    }
    __syncthreads();
    if (kp == 0) {
#pragma unroll
      for (int r = 0; r < 4; ++r)
        gs[(bt << 4) + (quad << 2) + r][hc] += acc0[r] + acc1[r];
    }
    __syncthreads();

    // ---- pointwise LSTM update (fp32): thread -> (b, 2 cols) ----
    if (tid < 128) {
      const float fp0 = gs[pb][li] + bf0,      fp1 = gs[pb][li + 1] + bf1;
      const float ip0 = gs[pb][4 + li] + bi0,  ip1 = gs[pb][5 + li] + bi1;
      const float op0 = gs[pb][8 + li] + bo0,  op1 = gs[pb][9 + li] + bo1;
      const float gp0 = gs[pb][12 + li] + bg0, gp1 = gs[pb][13 + li] + bg1;
      const float fs0 = 1.0f / (1.0f + __expf(-fp0)), fs1 = 1.0f / (1.0f + __expf(-fp1));
      const float is0 = 1.0f / (1.0f + __expf(-ip0)), is1 = 1.0f / (1.0f + __expf(-ip1));
      const float os0 = 1.0f / (1.0f + __expf(-op0)), os1 = 1.0f / (1.0f + __expf(-op1));
      const float gv0 = tanhf(gp0), gv1 = tanhf(gp1);
      cr0 = fs0 * cr0 + is0 * gv0;
      cr1 = fs1 * cr1 + is1 * gv1;
      const float h0 = os0 * tanhf(cr0), h1 = os1 * tanhf(cr1);
      // out: plain store (dirty L2, flushed at kernel end; never read here)
      float2 ov; ov.x = h0; ov.y = h1;
      *(float2*)(out + (((size_t)t) << 16) + ((size_t)pb << 10) + plA) = ov;
      // h: write-through sc1 store -> L3 (no wbl2 needed)
      union { __hip_bfloat16 b[2]; unsigned int u; } hu;
      hu.b[0] = __float2bfloat16(h0);
      hu.b[1] = __float2bfloat16(h1);
      __hip_bfloat16* hw = (t & 1) ? hb1 : hb0;
      __hip_atomic_store((unsigned int*)(hw + ((size_t)pb << 10) + plA), hu.u,
                         __ATOMIC_RELAXED, __HIP_MEMORY_SCOPE_AGENT);
    }
    asm volatile("s_waitcnt vmcnt(0)" ::: "memory");  // h committed to L3
    __syncthreads();                                  // all waves' stores drained
    if (tid == 0)
      __hip_atomic_store(&flags[bid], t + 1, __ATOMIC_RELAXED,
                         __HIP_MEMORY_SCOPE_AGENT);
  }
}

// ---------------------------------------------------------------------------
extern "C" void kernel_launch(void* const* d_in, const int* in_sizes, int n_in,
                              void* d_out, int out_size, void* d_ws, size_t ws_size,
                              hipStream_t stream) {
  const float* x   = (const float*)d_in[0];
  const float* Wf  = (const float*)d_in[1];
  const float* bfv = (const float*)d_in[2];
  const float* Wi  = (const float*)d_in[3];
  const float* biv = (const float*)d_in[4];
  const float* Wo  = (const float*)d_in[5];
  const float* bov = (const float*)d_in[6];
  const float* Wg  = (const float*)d_in[7];
  const float* bgv = (const float*)d_in[8];
  float* out = (float*)d_out;

  // ws: Wt bf16 [4096][2048] (16 MB) | xbf (64 MB) | hb0,hb1 (128 KB ea) | flags
  __hip_bfloat16* Wt  = (__hip_bfloat16*)d_ws;
  __hip_bfloat16* xbf = Wt + (size_t)4096 * 2048;
  __hip_bfloat16* hb0 = xbf + (size_t)TT * BB * LL;
  __hip_bfloat16* hb1 = hb0 + (size_t)BB * LL;
  int* flags = (int*)(hb1 + (size_t)BB * LL);

  transpose_w<<<dim3(64, 32, 4), 256, 0, stream>>>(Wf, Wi, Wo, Wg, Wt);
  xconv<<<dim3((TT * BB * LL) / 4 / 256), 256, 0, stream>>>(x, xbf);
  hipMemsetAsync(flags, 0, 256 * sizeof(int), stream);

  lstm_persist<<<256, 512, 0, stream>>>(xbf, Wt, bfv, biv, bov, bgv,
                                        out, hb0, hb1, flags);
}

// Round 4
// 5467.613 us; speedup vs baseline: 2.6921x; 1.5683x over previous
//
#include <hip/hip_runtime.h>
#include <hip/hip_bf16.h>
#include <cstdint>
#include <cstddef>

typedef short short8 __attribute__((ext_vector_type(8)));
typedef float f32x4 __attribute__((ext_vector_type(4)));
typedef int i32x4 __attribute__((ext_vector_type(4)));
typedef unsigned long long u64;
typedef unsigned int u32;

#define TT 512
#define BB 64
#define DD 1024
#define LL 1024

// ---------------------------------------------------------------------------
// Prep 1: transpose + convert 4 gate weights [2048,1024] fp32 -> Wt[c][k] bf16,
// c = g*1024 + l, k contiguous. (Verified R0/R1/R3.)
// ---------------------------------------------------------------------------
__global__ __launch_bounds__(256) void transpose_w(
    const float* __restrict__ Wf, const float* __restrict__ Wi,
    const float* __restrict__ Wo, const float* __restrict__ Wg,
    __hip_bfloat16* __restrict__ Wt) {
  __shared__ float tile[32][33];
  const int g = blockIdx.z;
  const float* W = (g == 0) ? Wf : (g == 1) ? Wi : (g == 2) ? Wo : Wg;
  const int k0 = blockIdx.x * 32, l0 = blockIdx.y * 32;
  const int c = threadIdx.x & 31, r0 = threadIdx.x >> 5;
#pragma unroll
  for (int rr = 0; rr < 4; ++rr) {
    const int kk = r0 + rr * 8;
    tile[kk][c] = W[(size_t)(k0 + kk) * LL + (l0 + c)];
  }
  __syncthreads();
#pragma unroll
  for (int rr = 0; rr < 4; ++rr) {
    const int ll = r0 + rr * 8;
    Wt[((size_t)(g * LL + l0 + ll) << 11) + (k0 + c)] = __float2bfloat16(tile[c][ll]);
  }
}

// ---------------------------------------------------------------------------
// Prep 2: x fp32 -> bf16.
// ---------------------------------------------------------------------------
__global__ __launch_bounds__(256) void xconv(const float* __restrict__ x,
                                             __hip_bfloat16* __restrict__ xbf) {
  const size_t i = (size_t)blockIdx.x * 256 + threadIdx.x;
  const float4 v = ((const float4*)x)[i];
  union { __hip_bfloat16 b[4]; uint2 u; } o;
  o.b[0] = __float2bfloat16(v.x);
  o.b[1] = __float2bfloat16(v.y);
  o.b[2] = __float2bfloat16(v.z);
  o.b[3] = __float2bfloat16(v.w);
  ((uint2*)xbf)[i] = o.u;
}

// ---------------------------------------------------------------------------
// PERSISTENT LSTM v4.
// 256 blocks (1/CU) x 512 thr. Wave (bt=w&3, kp=w>>2): kp=0 x-half, kp=1 h-half.
// vs v3 (proven correct, 16us/step):
//  (a) Only wave 4 polls flags (dwordx4 sc0 sc1, 64 lanes x 4 flags = all 256),
//      broadcasts via LDS epoch; waves 5-7 ds-spin. 256x less L3 poll traffic.
//  (b) h_t block-major: [chunk=bid][row 64][col 4] bf16 -> each block writes
//      one contiguous 512B (full lines, no L3 RMW write amplification).
//  (c) Virgin h buffer per step (hball, 64 MB): written once (sc1 write-
//      through), read only after flag -> readers use PLAIN CACHED loads
//      (no stale-L2 copy can exist within a dispatch; dispatch-start acquire
//      invalidates L2 across runs). First reader/XCD pulls L3, rest hit L2.
// Writer order: sc1 h stores -> vmcnt(0) -> __syncthreads -> tid0 sc1 flag.
// All spins bounded: failure shows as wrong numbers, never a hang.
// ---------------------------------------------------------------------------
__global__ __launch_bounds__(512, 2) void lstm_persist(
    const __hip_bfloat16* __restrict__ xbf, const __hip_bfloat16* __restrict__ Wt,
    const float* __restrict__ bfv, const float* __restrict__ biv,
    const float* __restrict__ bov, const float* __restrict__ bgv,
    float* __restrict__ out, __hip_bfloat16* __restrict__ hball,
    int* __restrict__ flags) {
  __shared__ float gs[64][17];  // +1 pad
  __shared__ int ep;

  const int tid = threadIdx.x;
  const int lane = tid & 63, w = tid >> 6;
  const int quad = lane >> 4, hc = lane & 15;
  const int bt = w & 3, kp = w >> 2;
  const int bid = blockIdx.x;
  const int l0 = bid * 4;

  if (tid == 0) ep = 0;

  // B fragments: col(hc) = (hc>>2)*1024 + l0 + (hc&3), k-window kp*1024..
  const int col = ((hc >> 2) << 10) + l0 + (hc & 3);
  const __hip_bfloat16* wb = Wt + ((size_t)col << 11) + (kp << 10) + quad * 8;
  short8 Bf[32];
#pragma unroll
  for (int i = 0; i < 32; ++i) Bf[i] = *(const short8*)(wb + i * 32);

  const int rowoff = (bt << 4) + hc;  // batch row this lane loads

  // ---- pointwise persistent state: tid<128 -> (b = tid>>1, 2 latent cols) ----
  const int pb = tid >> 1, li = (tid & 1) << 1;
  const int plA = l0 + li;
  float cr0 = 0.f, cr1 = 0.f;
  float bf0 = 0, bf1 = 0, bi0 = 0, bi1 = 0, bo0 = 0, bo1 = 0, bg0 = 0, bg1 = 0;
  if (tid < 128) {
    bf0 = bfv[plA]; bf1 = bfv[plA + 1];
    bi0 = biv[plA]; bi1 = biv[plA + 1];
    bo0 = bov[plA]; bo1 = bov[plA + 1];
    bg0 = bgv[plA]; bg1 = bgv[plA + 1];
  }
  __syncthreads();  // ep init visible

  for (int t = 0; t < TT; ++t) {
    f32x4 acc0 = {}, acc1 = {};

    if (kp == 0) {
      // ---- x_t GEMM half: plain cached bf16 loads, depth-2 prefetch ----
      const __hip_bfloat16* za = xbf + ((size_t)t << 16) + ((size_t)rowoff << 10) + quad * 8;
      short8 Af[2][8];
#pragma unroll
      for (int i = 0; i < 8; ++i) Af[0][i] = *(const short8*)(za + i * 32);
#pragma unroll
      for (int g = 0; g < 4; ++g) {
        const int cur = g & 1, nxt = cur ^ 1;
        if (g < 3) {
#pragma unroll
          for (int i = 0; i < 8; ++i)
            Af[nxt][i] = *(const short8*)(za + (g + 1) * 256 + i * 32);
        }
#pragma unroll
        for (int i = 0; i < 8; ++i) {
          if (i & 1)
            acc1 = __builtin_amdgcn_mfma_f32_16x16x32_bf16(Af[cur][i], Bf[g * 8 + i], acc1, 0, 0, 0);
          else
            acc0 = __builtin_amdgcn_mfma_f32_16x16x32_bf16(Af[cur][i], Bf[g * 8 + i], acc0, 0, 0, 0);
        }
      }
    } else if (t > 0) {
      // ---- wait for step t-1: wave 4 polls, waves 5-7 ds-spin on LDS ep ----
      if (w == 4) {
        const int* fp4 = flags + (lane << 2);
        int ok = 0, spins = 0;
        while (!ok && spins < (1 << 16)) {
          i32x4 f;
          asm volatile("global_load_dwordx4 %0, %1, off sc0 sc1"
                       : "=v"(f) : "v"(fp4));
          asm volatile("s_waitcnt vmcnt(0)" ::: "memory");
          ok = __all((f[0] >= t) & (f[1] >= t) & (f[2] >= t) & (f[3] >= t));
          if (!ok) { __builtin_amdgcn_s_sleep(2); ++spins; }
        }
        __hip_atomic_store(&ep, t, __ATOMIC_RELAXED, __HIP_MEMORY_SCOPE_WORKGROUP);
      } else {
        int spins = 0;
        while (__hip_atomic_load(&ep, __ATOMIC_RELAXED,
                                 __HIP_MEMORY_SCOPE_WORKGROUP) < t) {
          if (++spins > (1 << 22)) break;  // fail visible, never hang
        }
      }
      asm volatile("" ::: "memory");  // keep h loads below the spin

      // ---- h GEMM half: plain cached u64 loads from virgin h[t-1] ----
      // elem(r,c) at chunk c>>2, offset r*4+(c&3)  =>  u64 idx = c0*16 + r
      const u64* hp = (const u64*)(hball + ((size_t)(t - 1) << 16)) + (quad << 7) + rowoff;
      union frag { short8 s; u64 u[2]; };
      frag Ah[2][8];
#pragma unroll
      for (int i = 0; i < 8; ++i) {
        Ah[0][i].u[0] = hp[i * 512];
        Ah[0][i].u[1] = hp[i * 512 + 64];
      }
#pragma unroll
      for (int g = 0; g < 4; ++g) {
        const int cur = g & 1, nxt = cur ^ 1;
        if (g < 3) {
#pragma unroll
          for (int i = 0; i < 8; ++i) {
            Ah[nxt][i].u[0] = hp[(g + 1) * 4096 + i * 512];
            Ah[nxt][i].u[1] = hp[(g + 1) * 4096 + i * 512 + 64];
          }
        }
#pragma unroll
        for (int i = 0; i < 8; ++i) {
          if (i & 1)
            acc1 = __builtin_amdgcn_mfma_f32_16x16x32_bf16(Ah[cur][i].s, Bf[g * 8 + i], acc1, 0, 0, 0);
          else
            acc0 = __builtin_amdgcn_mfma_f32_16x16x32_bf16(Ah[cur][i].s, Bf[g * 8 + i], acc0, 0, 0, 0);
        }
      }
    }
    // (kp==1, t==0: h = 0, acc stays 0)

    // ---- cross-wave (kp) reduction: C/D row=quad*4+r, col=hc ----
    if (kp == 1) {
#pragma unroll
      for (int r = 0; r < 4; ++r)
        gs[(bt << 4) + (quad << 2) + r][hc] = acc0[r] + acc1[r];
    }
    __syncthreads();
    if (kp == 0) {
#pragma unroll
      for (int r = 0; r < 4; ++r)
        gs[(bt << 4) + (quad << 2) + r][hc] += acc0[r] + acc1[r];
    }
    __syncthreads();

    // ---- pointwise LSTM update (fp32): thread -> (b, 2 cols) ----
    if (tid < 128) {
      const float fp0 = gs[pb][li] + bf0,      fp1 = gs[pb][li + 1] + bf1;
      const float ip0 = gs[pb][4 + li] + bi0,  ip1 = gs[pb][5 + li] + bi1;
      const float op0 = gs[pb][8 + li] + bo0,  op1 = gs[pb][9 + li] + bo1;
      const float gp0 = gs[pb][12 + li] + bg0, gp1 = gs[pb][13 + li] + bg1;
      const float fs0 = 1.0f / (1.0f + __expf(-fp0)), fs1 = 1.0f / (1.0f + __expf(-fp1));
      const float is0 = 1.0f / (1.0f + __expf(-ip0)), is1 = 1.0f / (1.0f + __expf(-ip1));
      const float os0 = 1.0f / (1.0f + __expf(-op0)), os1 = 1.0f / (1.0f + __expf(-op1));
      const float gv0 = tanhf(gp0), gv1 = tanhf(gp1);
      cr0 = fs0 * cr0 + is0 * gv0;
      cr1 = fs1 * cr1 + is1 * gv1;
      const float h0 = os0 * tanhf(cr0), h1 = os1 * tanhf(cr1);
      // out: plain store (dirty L2, flushed at dispatch end; never read here)
      float2 ov; ov.x = h0; ov.y = h1;
      *(float2*)(out + (((size_t)t) << 16) + ((size_t)pb << 10) + plA) = ov;
      // h: block-major chunk, contiguous 512B/block, sc1 write-through to L3
      union { __hip_bfloat16 b[2]; u32 uu; } hu;
      hu.b[0] = __float2bfloat16(h0);
      hu.b[1] = __float2bfloat16(h1);
      u32* hwp = (u32*)(hball + ((size_t)t << 16));
      __hip_atomic_store(hwp + (bid << 7) + tid, hu.uu,
                         __ATOMIC_RELAXED, __HIP_MEMORY_SCOPE_AGENT);
    }
    asm volatile("s_waitcnt vmcnt(0)" ::: "memory");  // h committed to L3
    __syncthreads();                                  // all waves drained
    if (tid == 0)
      __hip_atomic_store(&flags[bid], t + 1, __ATOMIC_RELAXED,
                         __HIP_MEMORY_SCOPE_AGENT);
  }
}

// ---------------------------------------------------------------------------
extern "C" void kernel_launch(void* const* d_in, const int* in_sizes, int n_in,
                              void* d_out, int out_size, void* d_ws, size_t ws_size,
                              hipStream_t stream) {
  const float* x   = (const float*)d_in[0];
  const float* Wf  = (const float*)d_in[1];
  const float* bfv = (const float*)d_in[2];
  const float* Wi  = (const float*)d_in[3];
  const float* biv = (const float*)d_in[4];
  const float* Wo  = (const float*)d_in[5];
  const float* bov = (const float*)d_in[6];
  const float* Wg  = (const float*)d_in[7];
  const float* bgv = (const float*)d_in[8];
  float* out = (float*)d_out;

  // ws: Wt 16MB | xbf 64MB | hball 64MB (512 virgin 128KB h buffers) | flags 1KB
  __hip_bfloat16* Wt    = (__hip_bfloat16*)d_ws;
  __hip_bfloat16* xbf   = Wt + (size_t)4096 * 2048;
  __hip_bfloat16* hball = xbf + (size_t)TT * BB * LL;
  int* flags = (int*)(hball + (size_t)TT * 65536);

  transpose_w<<<dim3(64, 32, 4), 256, 0, stream>>>(Wf, Wi, Wo, Wg, Wt);
  xconv<<<dim3((TT * BB * LL) / 4 / 256), 256, 0, stream>>>(x, xbf);
  hipMemsetAsync(flags, 0, 256 * sizeof(int), stream);

  lstm_persist<<<256, 512, 0, stream>>>(xbf, Wt, bfv, biv, bov, bgv,
                                        out, hball, flags);
}

// Round 5
// 4386.136 us; speedup vs baseline: 3.3559x; 1.2466x over previous
//
#include <hip/hip_runtime.h>
#include <hip/hip_bf16.h>
#include <cstdint>
#include <cstddef>

typedef short short8 __attribute__((ext_vector_type(8)));
typedef float f32x4 __attribute__((ext_vector_type(4)));
typedef int i32x4 __attribute__((ext_vector_type(4)));
typedef unsigned long long u64;
typedef unsigned int u32;

#define TT 512
#define BB 64
#define DD 1024
#define LL 1024

// ---------------------------------------------------------------------------
// Prep 1: transpose + convert 4 gate weights [2048,1024] fp32 -> Wt[c][k] bf16,
// c = g*1024 + l, k contiguous. (Verified R0/R1/R3/R4.)
// ---------------------------------------------------------------------------
__global__ __launch_bounds__(256) void transpose_w(
    const float* __restrict__ Wf, const float* __restrict__ Wi,
    const float* __restrict__ Wo, const float* __restrict__ Wg,
    __hip_bfloat16* __restrict__ Wt) {
  __shared__ float tile[32][33];
  const int g = blockIdx.z;
  const float* W = (g == 0) ? Wf : (g == 1) ? Wi : (g == 2) ? Wo : Wg;
  const int k0 = blockIdx.x * 32, l0 = blockIdx.y * 32;
  const int c = threadIdx.x & 31, r0 = threadIdx.x >> 5;
#pragma unroll
  for (int rr = 0; rr < 4; ++rr) {
    const int kk = r0 + rr * 8;
    tile[kk][c] = W[(size_t)(k0 + kk) * LL + (l0 + c)];
  }
  __syncthreads();
#pragma unroll
  for (int rr = 0; rr < 4; ++rr) {
    const int ll = r0 + rr * 8;
    Wt[((size_t)(g * LL + l0 + ll) << 11) + (k0 + c)] = __float2bfloat16(tile[c][ll]);
  }
}

// ---------------------------------------------------------------------------
// Prep 2: x fp32 -> bf16.
// ---------------------------------------------------------------------------
__global__ __launch_bounds__(256) void xconv(const float* __restrict__ x,
                                             __hip_bfloat16* __restrict__ xbf) {
  const size_t i = (size_t)blockIdx.x * 256 + threadIdx.x;
  const float4 v = ((const float4*)x)[i];
  union { __hip_bfloat16 b[4]; uint2 u; } o;
  o.b[0] = __float2bfloat16(v.x);
  o.b[1] = __float2bfloat16(v.y);
  o.b[2] = __float2bfloat16(v.z);
  o.b[3] = __float2bfloat16(v.w);
  ((uint2*)xbf)[i] = o.u;
}

// ---------------------------------------------------------------------------
// PERSISTENT LSTM v5 — role-split waves, LDS-resident weights.
// 256 blocks (1/CU) x 512 thr. Protocol identical to v4 (proven):
//   virgin per-step h buffers (sc1 write-through, plain cached reads),
//   wave0 polls 256 flags via dwordx4 sc0 sc1, LDS ep broadcast, bounded spins.
// New structure:
//   Waves 0-3 (bt=w): h-GEMM (k 1024..2047) + pointwise + h/out stores.
//     Lane owns (b = bt*16 + lane/4, l = l0 + lane%4); c stays in register.
//     Gate transpose via per-wave LDS tile gw[bt] (no block barrier).
//   Waves 4-7 (bt=w-4): x-GEMM (k 0..1023) ONE STEP AHEAD -> gsx[par] LDS.
//     Off the critical path entirely; handed off by the end-of-step barrier.
//   Weights: 64 KB LDS, fragment-layout wf[kp][j][lane] (16B/lane,
//     consecutive-lane-consecutive-16B -> conflict-free ds_read_b128).
// One __syncthreads per step (gsx handoff + store-drain before flag).
// ---------------------------------------------------------------------------
__global__ __launch_bounds__(512, 2) void lstm_persist(
    const __hip_bfloat16* __restrict__ xbf, const __hip_bfloat16* __restrict__ Wt,
    const float* __restrict__ bfv, const float* __restrict__ biv,
    const float* __restrict__ bov, const float* __restrict__ bgv,
    float* __restrict__ out, __hip_bfloat16* __restrict__ hball,
    int* __restrict__ flags) {
  __shared__ short8 wf[4096];       // 64 KB weights: [kp][frag j][lane]
  __shared__ float gw[4][16][17];   // per-h-wave gate transpose tile
  __shared__ float gsx[2][64][17];  // x-partial double buffer
  __shared__ int ep;

  const int tid = threadIdx.x;
  const int lane = tid & 63, w = tid >> 6;
  const int quad = lane >> 4, hc = lane & 15;
  const bool isH = (w < 4);
  const int bt = w & 3;
  const int kp = isH ? 1 : 0;
  const int bid = blockIdx.x;
  const int l0 = bid * 4;

  if (tid == 0) ep = 0;

  // ---- stage weights into LDS (wave0: kp=1 half, wave4: kp=0 half) ----
  const int col = ((hc >> 2) << 10) + l0 + (hc & 3);
  if (w == 0 || w == 4) {
    const __hip_bfloat16* wb = Wt + ((size_t)col << 11) + (kp << 10) + quad * 8;
#pragma unroll
    for (int j = 0; j < 32; ++j)
      wf[(kp << 11) + (j << 6) + lane] = *(const short8*)(wb + j * 32);
  }

  const int rowoff = (bt << 4) + hc;  // batch row this lane loads (A-frag)

  // ---- pointwise state (h-waves): lane -> (b = bt*16+row16, l = l0+lc) ----
  const int row16 = lane >> 2, lc = lane & 3;
  const int pl = l0 + lc;
  float cr = 0.f, bfr = 0.f, bir = 0.f, bor = 0.f, bgr = 0.f;
  if (isH) { bfr = bfv[pl]; bir = biv[pl]; bor = bov[pl]; bgr = bgv[pl]; }

  __syncthreads();  // weights staged, ep init visible

  // x-GEMM for step tt -> gsx[tt&1]  (runs on waves 4-7)
  auto xgemm = [&](int tt) {
    const __hip_bfloat16* za =
        xbf + ((size_t)tt << 16) + ((size_t)rowoff << 10) + quad * 8;
    f32x4 a0 = {}, a1 = {};
    short8 Af[2][8];
#pragma unroll
    for (int i = 0; i < 8; ++i) Af[0][i] = *(const short8*)(za + i * 32);
#pragma unroll
    for (int g = 0; g < 4; ++g) {
      const int cur = g & 1, nxt = cur ^ 1;
      if (g < 3) {
#pragma unroll
        for (int i = 0; i < 8; ++i)
          Af[nxt][i] = *(const short8*)(za + (g + 1) * 256 + i * 32);
      }
#pragma unroll
      for (int i = 0; i < 8; ++i) {
        const short8 bb = wf[((g << 3) + i) * 64 + lane];  // kp=0 base
        if (i & 1)
          a1 = __builtin_amdgcn_mfma_f32_16x16x32_bf16(Af[cur][i], bb, a1, 0, 0, 0);
        else
          a0 = __builtin_amdgcn_mfma_f32_16x16x32_bf16(Af[cur][i], bb, a0, 0, 0, 0);
      }
    }
    const int par = tt & 1;
#pragma unroll
    for (int r = 0; r < 4; ++r)
      gsx[par][(bt << 4) + (quad << 2) + r][hc] = a0[r] + a1[r];
  };

  if (!isH) xgemm(0);  // prologue: x-partial for step 0
  __syncthreads();

  for (int t = 0; t < TT; ++t) {
    if (!isH) {
      // ---- x prefetch for step t+1 (off critical path) ----
      if (t + 1 < TT) xgemm(t + 1);
    } else {
      f32x4 a0 = {}, a1 = {};
      if (t > 0) {
        // ---- wait for step t-1: wave0 polls, waves 1-3 ds-spin ----
        if (w == 0) {
          const int* fp4 = flags + (lane << 2);
          int ok = 0, spins = 0;
          while (!ok && spins < (1 << 14)) {
            i32x4 f;
            asm volatile("global_load_dwordx4 %0, %1, off sc0 sc1"
                         : "=v"(f) : "v"(fp4));
            asm volatile("s_waitcnt vmcnt(0)" ::: "memory");
            ok = __all((f[0] >= t) & (f[1] >= t) & (f[2] >= t) & (f[3] >= t));
            if (!ok) { __builtin_amdgcn_s_sleep(1); ++spins; }
          }
          __hip_atomic_store(&ep, t, __ATOMIC_RELAXED, __HIP_MEMORY_SCOPE_WORKGROUP);
        } else {
          int spins = 0;
          while (__hip_atomic_load(&ep, __ATOMIC_RELAXED,
                                   __HIP_MEMORY_SCOPE_WORKGROUP) < t) {
            if (++spins > (1 << 22)) break;  // fail visible, never hang
          }
        }
        asm volatile("" ::: "memory");  // keep h loads below the spin

        // ---- h-GEMM: plain cached u64 loads from virgin h[t-1] ----
        const u64* hp = (const u64*)(hball + ((size_t)(t - 1) << 16)) +
                        (quad << 7) + rowoff;
        union frag { short8 s; u64 u[2]; };
        frag Ah[2][8];
#pragma unroll
        for (int i = 0; i < 8; ++i) {
          Ah[0][i].u[0] = hp[i * 512];
          Ah[0][i].u[1] = hp[i * 512 + 64];
        }
#pragma unroll
        for (int g = 0; g < 4; ++g) {
          const int cur = g & 1, nxt = cur ^ 1;
          if (g < 3) {
#pragma unroll
            for (int i = 0; i < 8; ++i) {
              Ah[nxt][i].u[0] = hp[(g + 1) * 4096 + i * 512];
              Ah[nxt][i].u[1] = hp[(g + 1) * 4096 + i * 512 + 64];
            }
          }
#pragma unroll
          for (int i = 0; i < 8; ++i) {
            const short8 bb = wf[2048 + ((g << 3) + i) * 64 + lane];  // kp=1
            if (i & 1)
              a1 = __builtin_amdgcn_mfma_f32_16x16x32_bf16(Ah[cur][i].s, bb, a1, 0, 0, 0);
            else
              a0 = __builtin_amdgcn_mfma_f32_16x16x32_bf16(Ah[cur][i].s, bb, a0, 0, 0, 0);
          }
        }
      }

      // ---- gw = h-partial + x-partial (wave-local transpose tile) ----
#pragma unroll
      for (int r = 0; r < 4; ++r)
        gw[bt][(quad << 2) + r][hc] =
            a0[r] + a1[r] + gsx[t & 1][(bt << 4) + (quad << 2) + r][hc];

      // ---- pointwise (same wave; in-wave LDS ordering only) ----
      const float fp = gw[bt][row16][lc] + bfr;
      const float ip = gw[bt][row16][4 + lc] + bir;
      const float op = gw[bt][row16][8 + lc] + bor;
      const float gp = gw[bt][row16][12 + lc] + bgr;
      const float fs = 1.0f / (1.0f + __expf(-fp));
      const float is = 1.0f / (1.0f + __expf(-ip));
      const float os = 1.0f / (1.0f + __expf(-op));
      const float gv = tanhf(gp);
      cr = fs * cr + is * gv;
      const float h = os * tanhf(cr);
      const int b = (bt << 4) + row16;
      // out: plain fp32 store (dirty L2, flushed at dispatch end)
      out[((size_t)t << 16) + ((size_t)b << 10) + pl] = h;
      // h: pack pair via shfl, u32 sc1 write-through, block-major chunk
      const float hn = __shfl_xor(h, 1);
      if ((lc & 1) == 0) {
        union { __hip_bfloat16 x[2]; u32 u; } hu;
        hu.x[0] = __float2bfloat16(h);
        hu.x[1] = __float2bfloat16(hn);
        u32* hwp = (u32*)(hball + ((size_t)t << 16));
        __hip_atomic_store(hwp + (bid << 7) + (b << 1) + (lc >> 1), hu.u,
                           __ATOMIC_RELAXED, __HIP_MEMORY_SCOPE_AGENT);
      }
    }

    asm volatile("s_waitcnt vmcnt(0)" ::: "memory");  // h committed to L3
    __syncthreads();                                  // all waves drained + gsx handoff
    if (tid == 0)
      __hip_atomic_store(&flags[bid], t + 1, __ATOMIC_RELAXED,
                         __HIP_MEMORY_SCOPE_AGENT);
  }
}

// ---------------------------------------------------------------------------
extern "C" void kernel_launch(void* const* d_in, const int* in_sizes, int n_in,
                              void* d_out, int out_size, void* d_ws, size_t ws_size,
                              hipStream_t stream) {
  const float* x   = (const float*)d_in[0];
  const float* Wf  = (const float*)d_in[1];
  const float* bfv = (const float*)d_in[2];
  const float* Wi  = (const float*)d_in[3];
  const float* biv = (const float*)d_in[4];
  const float* Wo  = (const float*)d_in[5];
  const float* bov = (const float*)d_in[6];
  const float* Wg  = (const float*)d_in[7];
  const float* bgv = (const float*)d_in[8];
  float* out = (float*)d_out;

  // ws: Wt 16MB | xbf 64MB | hball 64MB (512 virgin 128KB h buffers) | flags 1KB
  __hip_bfloat16* Wt    = (__hip_bfloat16*)d_ws;
  __hip_bfloat16* xbf   = Wt + (size_t)4096 * 2048;
  __hip_bfloat16* hball = xbf + (size_t)TT * BB * LL;
  int* flags = (int*)(hball + (size_t)TT * 65536);

  transpose_w<<<dim3(64, 32, 4), 256, 0, stream>>>(Wf, Wi, Wo, Wg, Wt);
  xconv<<<dim3((TT * BB * LL) / 4 / 256), 256, 0, stream>>>(x, xbf);
  hipMemsetAsync(flags, 0, 256 * sizeof(int), stream);

  lstm_persist<<<256, 512, 0, stream>>>(xbf, Wt, bfv, biv, bov, bgv,
                                        out, hball, flags);
}